// Round 10
// baseline (69.770 us; speedup 1.0000x reference)
//
#include <hip/hip_runtime.h>

#define BATCH   8
#define HH      512
#define WW      512
#define IMGPIX  (HH * WW)          // 262144 = 1<<18
#define NPIX    (BATCH * IMGPIX)   // 2097152
#define NWORDS  (NPIX / 64)        // 32768 packed words
#define WPR     8                  // 64-bit words per 512-px row
#define LDSTR   9                  // padded LDS row stride in words
#define FPSCALE 262144.0           // 2^18 fixed-point scale for i64 reduction
#define MAXPAIR 256

typedef unsigned long long u64;
typedef unsigned int u32;

// ---------------- kernel 1: CE loss + packed binary mask + zero accumulators ----------------
__global__ void prep_kernel(const float* __restrict__ pred, const int* __restrict__ target,
                            float* __restrict__ L, u64* __restrict__ xp,
                            u64* __restrict__ acc64, u32* __restrict__ ticket) {
    int i = blockIdx.x * blockDim.x + threadIdx.x;
    if (i == 0) { acc64[0] = 0ULL; ticket[0] = 0u; }
    if (i >= NPIX) return;
    int b = i >> 18;
    int hw = i & (IMGPIX - 1);
    float p0 = pred[((size_t)(2 * b) << 18) + hw];
    float p1 = pred[((size_t)(2 * b + 1) << 18) + hw];
    float m = fmaxf(p0, p1);
    float lse = m + logf(expf(p0 - m) + expf(p1 - m));
    int t = target[i];
    L[i] = lse - (t ? p1 : p0);            // -log_softmax[target]
    u64 word = __ballot(p1 > p0);          // 64 consecutive pixels per wave
    if ((threadIdx.x & 63) == 0) xp[i >> 6] = word;
}

// ---------------- bit-sliced helpers ----------------
#define FA(a,b,c,s,cy) { u64 _x = (a)^(b); (s) = _x^(c); (cy) = ((a)&(b)) | ((c)&_x); }
#define HA(a,b,s,cy)   { (s) = (a)^(b); (cy) = (a)&(b); }

// One ZS substep over a row of 8 words held in M[]; U/D are neighbor rows.
// Updates M in place; returns OR of deleted bits in *chout and per-col changed mask.
template<int FIRST>
__device__ __forceinline__ u32 zs_row(const u64* __restrict__ U, u64* __restrict__ M,
                                      const u64* __restrict__ D, u64* __restrict__ chout)
{
    u64 ch = 0;
    u32 cm = 0;
    #pragma unroll
    for (int k = 0; k < WPR; ++k) {
        u64 Mc = M[k];
        if (Mc == 0ULL) continue;
        u64 Uc = U[k], Dc = D[k];
        u64 Up = k     ? U[k-1] : 0ULL;
        u64 Mp = k     ? M[k-1] : 0ULL;
        u64 Dp = k     ? D[k-1] : 0ULL;
        u64 Un = k < 7 ? U[k+1] : 0ULL;
        u64 Mn = k < 7 ? M[k+1] : 0ULL;
        u64 Dn = k < 7 ? D[k+1] : 0ULL;
        u64 P2 = Uc, P6 = Dc;
        u64 P3 = (Uc >> 1) | (Un << 63);
        u64 P4 = (Mc >> 1) | (Mn << 63);
        u64 P5 = (Dc >> 1) | (Dn << 63);
        u64 P9 = (Uc << 1) | (Up >> 63);
        u64 P8 = (Mc << 1) | (Mp >> 63);
        u64 P7 = (Dc << 1) | (Dp >> 63);

        u64 sa,ca, sb,cb, sc,cc, b0,cd, sd,ce, b1,cf, b2,b3;
        FA(P2,P3,P4, sa,ca);
        FA(P5,P6,P7, sb,cb);
        FA(P8,P9,sa, sc,cc);
        HA(sb,sc,    b0,cd);
        FA(ca,cb,cc, sd,ce);
        HA(sd,cd,    b1,cf);
        HA(ce,cf,    b2,b3);
        u64 ge2 = b1 | b2 | b3;
        u64 le6 = ~(b3 | (b0 & b1 & b2));

        u64 e, seen, two = 0;
        seen = (~P2) & P3;
        e = (~P3) & P4; two |= seen & e; seen |= e;
        e = (~P4) & P5; two |= seen & e; seen |= e;
        e = (~P5) & P6; two |= seen & e; seen |= e;
        e = (~P6) & P7; two |= seen & e; seen |= e;
        e = (~P7) & P8; two |= seen & e; seen |= e;
        e = (~P8) & P9; two |= seen & e; seen |= e;
        e = (~P9) & P2; two |= seen & e; seen |= e;
        u64 A1 = seen & ~two;

        u64 c34;
        if (FIRST) { u64 t = P4 & P6; c34 = t & (P2 | P8); }
        else       { u64 t = P2 & P8; c34 = t & (P4 | P6); }

        u64 del = Mc & ge2 & le6 & A1 & ~c34;
        M[k] = Mc ^ del;
        ch |= del;
        cm |= (del != 0ULL) ? (1u << k) : 0u;
    }
    *chout = ch;
    return cm;
}

// ---------------- kernel 2: single-block-per-image skeletonize + packed endpoints ----------------
// 8 blocks x 512 threads (thread = row). Own row in registers; wave-granularity activity gating:
// a word can change at substep s only if its 3x3 word-neighborhood changed at s-1 or s-2
// (monotone deletion + same-parity locality). chg[h] = {prev substep changed cols (lo byte),
// substep-before (hi byte)}. The whole substep body is branch-guarded per thread, so a wave
// whose 64 rows are all quiet skips issue entirely (s_cbranch_execz).
__global__ __launch_bounds__(512)
void skel_kernel(const u64* __restrict__ xp, u64* __restrict__ eg)
{
    __shared__ u64 img[(HH + 2) * LDSTR];  // guard rows 0 and HH+1 stay zero: 37,008 B
    __shared__ u32 chg[HH + 2];            // change history per row (+guards): 2,056 B
    const int b = blockIdx.x;
    const int h = threadIdx.x;
    const int base = (h + 1) * LDSTR;      // own row origin in LDS

    // zero guard rows / guard history once
    if (h < 2 * LDSTR) {
        int idx = (h < LDSTR) ? h : ((HH + 1) * LDSTR + (h - LDSTR));
        img[idx] = 0ULL;
    }
    if (h == 0) { chg[0] = 0u; chg[HH + 1] = 0u; }
    u32 mych = 0xFFFFu;                    // full history -> first two substeps run everywhere
    chg[h + 1] = mych;

    u64 M[WPR], U[WPR], D[WPR];
    const u64* src = xp + ((size_t)b << 12) + (size_t)h * WPR;
    #pragma unroll
    for (int k = 0; k < WPR; ++k) { M[k] = src[k]; img[base + k] = M[k]; }
    __syncthreads();

    for (int p = 0; p < MAXPAIR; ++p) {
        u64 chA = 0, chB = 0;

        // ---- substep A (first = true)
        {
            u32 m = chg[h] | mych | chg[h + 2];
            u32 mm = (m | (m >> 8)) & 0xFFu;
            u32 act = (mm | (mm << 1) | (mm >> 1)) & 0xFFu;
            if (act) {
                #pragma unroll
                for (int k = 0; k < WPR; ++k) { U[k] = img[base - LDSTR + k]; D[k] = img[base + LDSTR + k]; }
            }
            __syncthreads();                               // reads done before writes
            u32 cm = 0;
            if (act) {
                cm = zs_row<1>(U, M, D, &chA);
                if (chA) {
                    #pragma unroll
                    for (int k = 0; k < WPR; ++k) img[base + k] = M[k];
                }
            }
            mych = ((mych & 0xFFu) << 8) | cm;
            chg[h + 1] = mych;
            __syncthreads();                               // writes visible
        }

        // ---- substep B (first = false)
        {
            u32 m = chg[h] | mych | chg[h + 2];
            u32 mm = (m | (m >> 8)) & 0xFFu;
            u32 act = (mm | (mm << 1) | (mm >> 1)) & 0xFFu;
            if (act) {
                #pragma unroll
                for (int k = 0; k < WPR; ++k) { U[k] = img[base - LDSTR + k]; D[k] = img[base + LDSTR + k]; }
            }
            __syncthreads();
            u32 cm = 0;
            if (act) {
                cm = zs_row<0>(U, M, D, &chB);
                if (chB) {
                    #pragma unroll
                    for (int k = 0; k < WPR; ++k) img[base + k] = M[k];
                }
            }
            mych = ((mych & 0xFFu) << 8) | cm;
            chg[h + 1] = mych;
        }
        if (!__syncthreads_or((chA | chB) != 0ULL)) break; // pair deleted nothing anywhere
    }

    // ---- endpoints E = skel & (exactly one 8-neighbor); state: img + M regs (own row)
    #pragma unroll
    for (int k = 0; k < WPR; ++k) { U[k] = img[base - LDSTR + k]; D[k] = img[base + LDSTR + k]; }
    u64* egr = eg + ((size_t)b << 12) + (size_t)h * WPR;
    #pragma unroll
    for (int k = 0; k < WPR; ++k) {
        u64 Mc = M[k];
        u64 Uc = U[k], Dc = D[k];
        u64 Up = k     ? U[k-1] : 0ULL;
        u64 Mp = k     ? M[k-1] : 0ULL;
        u64 Dp = k     ? D[k-1] : 0ULL;
        u64 Un = k < 7 ? U[k+1] : 0ULL;
        u64 Mn = k < 7 ? M[k+1] : 0ULL;
        u64 Dn = k < 7 ? D[k+1] : 0ULL;
        u64 P2 = Uc, P6 = Dc;
        u64 P3 = (Uc >> 1) | (Un << 63);
        u64 P4 = (Mc >> 1) | (Mn << 63);
        u64 P5 = (Dc >> 1) | (Dn << 63);
        u64 P9 = (Uc << 1) | (Up >> 63);
        u64 P8 = (Mc << 1) | (Mp >> 63);
        u64 P7 = (Dc << 1) | (Dp >> 63);
        u64 e, seen, two = 0;
        seen = P2;
        e = P3; two |= seen & e; seen |= e;
        e = P4; two |= seen & e; seen |= e;
        e = P5; two |= seen & e; seen |= e;
        e = P6; two |= seen & e; seen |= e;
        e = P7; two |= seen & e; seen |= e;
        e = P8; two |= seen & e; seen |= e;
        e = P9; two |= seen & e; seen |= e;
        egr[k] = Mc & seen & ~two;             // exactly one neighbor
    }
}

// ---------------- packed 9x9 count helpers ----------------
struct Planes { u64 p0, p1, p2, p3; };

__device__ __forceinline__ Planes vcount9(const u64 r[9]) {
    u64 s0,c0, s1,c1, s2,c2, p0,t0, t1,t2, p1,t3, p2,p3;
    FA(r[0],r[1],r[2], s0,c0);
    FA(r[3],r[4],r[5], s1,c1);
    FA(r[6],r[7],r[8], s2,c2);
    FA(s0,s1,s2, p0,t0);
    FA(c0,c1,c2, t1,t2);
    HA(t0,t1,    p1,t3);
    HA(t2,t3,    p2,p3);
    Planes P; P.p0 = p0; P.p1 = p1; P.p2 = p2; P.p3 = p3; return P;
}

__device__ __forceinline__ u64 spread8(u64 bb) {
    u64 s = (bb * 0x0101010101010101ULL) & 0x8040201008040201ULL;
    return ((s + 0x7f7f7f7f7f7f7f7fULL) >> 7) & 0x0101010101010101ULL;
}

__device__ __forceinline__ u64 vbytes(const Planes& P, int g) {
    int s = 8 * g;
    return  spread8((P.p0 >> s) & 0xFFULL)
         + (spread8((P.p1 >> s) & 0xFFULL) << 1)
         + (spread8((P.p2 >> s) & 0xFFULL) << 2)
         + (spread8((P.p3 >> s) & 0xFFULL) << 3);
}

// ---------------- kernel 3: dense weighted sum ----------------
// w_i = 60*n_i + [n_i==0], n_i = 9x9 box count of E;  out = mean(w*L)
__global__ __launch_bounds__(256)
void final_kernel(const float* __restrict__ L, const u64* __restrict__ eg,
                  u64* __restrict__ acc64, u32* __restrict__ ticket,
                  float* __restrict__ out) {
    __shared__ float sm[256];
    int wi = blockIdx.x * blockDim.x + threadIdx.x;   // word index, 32768 total
    int b  = wi >> 12;                                // 4096 words / image
    int h  = (wi >> 3) & (HH - 1);
    int wc = wi & 7;
    const u64* img = eg + ((size_t)b << 12);

    u64 rows[3][9];
    #pragma unroll
    for (int dh = -4; dh <= 4; ++dh) {
        int hh = h + dh;
        bool okh = (unsigned)hh < (unsigned)HH;
        const u64* rp = img + hh * WPR;
        rows[0][dh + 4] = (okh && wc > 0) ? rp[wc - 1] : 0ULL;
        rows[1][dh + 4] = okh             ? rp[wc]     : 0ULL;
        rows[2][dh + 4] = (okh && wc < 7) ? rp[wc + 1] : 0ULL;
    }
    Planes Pm = vcount9(rows[0]);
    Planes Pc = vcount9(rows[1]);
    Planes Pp = vcount9(rows[2]);

    u64 v[10];
    v[0] = vbytes(Pm, 7);
    #pragma unroll
    for (int g = 0; g < 8; ++g) v[g + 1] = vbytes(Pc, g);
    v[9] = vbytes(Pp, 0);

    const float4* Lr = (const float4*)(L + ((size_t)wi << 6));
    float acc = 0.0f;
    #pragma unroll
    for (int g = 0; g < 8; ++g) {
        u64 a = v[g + 1], lo = v[g], hi = v[g + 2];
        u64 n = a;
        #pragma unroll
        for (int d = 1; d <= 4; ++d) {
            n += (a >> (8 * d)) | (hi << (64 - 8 * d));
            n += (a << (8 * d)) | (lo >> (64 - 8 * d));
        }
        float4 f0 = Lr[2 * g], f1 = Lr[2 * g + 1];
        #pragma unroll
        for (int j = 0; j < 8; ++j) {
            int cnt = (int)((n >> (8 * j)) & 0xFFULL);
            float wgt = cnt ? (float)(60 * cnt) : 1.0f;
            float lv = (j < 4) ? ((j == 0) ? f0.x : (j == 1) ? f0.y : (j == 2) ? f0.z : f0.w)
                               : ((j == 4) ? f1.x : (j == 5) ? f1.y : (j == 6) ? f1.z : f1.w);
            acc += wgt * lv;
        }
    }

    sm[threadIdx.x] = acc;
    __syncthreads();
    for (int s = 128; s > 0; s >>= 1) {
        if (threadIdx.x < s) sm[threadIdx.x] += sm[threadIdx.x + s];
        __syncthreads();
    }
    if (threadIdx.x == 0) {
        u64 vfx = (u64)(long long)llrintf(sm[0] * (float)FPSCALE);
        atomicAdd(acc64, vfx);
        __threadfence();
        u32 t = atomicAdd(ticket, 1u);
        if (t == (u32)(gridDim.x - 1)) {           // last block finishes
            __threadfence();
            u64 total = __hip_atomic_load(acc64, __ATOMIC_RELAXED, __HIP_MEMORY_SCOPE_AGENT);
            out[0] = (float)((double)(long long)total / (FPSCALE * (double)NPIX));
        }
    }
}

extern "C" void kernel_launch(void* const* d_in, const int* in_sizes, int n_in,
                              void* d_out, int out_size, void* d_ws, size_t ws_size,
                              hipStream_t stream) {
    const float* pred = (const float*)d_in[0];
    const int* target = (const int*)d_in[1];
    float* out = (float*)d_out;
    char* ws = (char*)d_ws;

    // ws layout (bytes):
    //   [0,        8388608)  L       float[NPIX]
    //   [8388608,  8650752)  xp      u64[NWORDS]  packed mask
    //   [8650752,  8912896)  eg      u64[NWORDS]  packed endpoints
    //   [8912896,  8912904)  acc64   u64
    //   [8912904,  8912908)  ticket  u32
    float* L    = (float*)(ws);
    u64* xp     = (u64*)(ws + 8388608);
    u64* eg     = (u64*)(ws + 8650752);
    u64* acc64  = (u64*)(ws + 8912896);
    u32* ticket = (u32*)(ws + 8912904);

    prep_kernel<<<dim3(NPIX / 256), dim3(256), 0, stream>>>(pred, target, L, xp, acc64, ticket);
    skel_kernel<<<dim3(BATCH), dim3(512), 0, stream>>>(xp, eg);
    final_kernel<<<dim3(NWORDS / 256), dim3(256), 0, stream>>>(L, eg, acc64, ticket, out);
}

// Round 11
// 59.450 us; speedup vs baseline: 1.1736x; 1.1736x over previous
//
#include <hip/hip_runtime.h>

#define BATCH   8
#define HH      512
#define WW      512
#define IMGPIX  (HH * WW)          // 262144 = 1<<18
#define NPIX    (BATCH * IMGPIX)   // 2097152
#define NWORDS  (NPIX / 64)        // 32768 packed words
#define WPR     8                  // 64-bit words per 512-px row
#define FPSCALE 262144.0           // 2^18 fixed-point scale for i64 reduction
#define MAXPAIR 256

typedef unsigned long long u64;
typedef unsigned int u32;

// ---------------- kernel 1: CE loss + packed binary mask + zero accumulators ----------------
__global__ void prep_kernel(const float* __restrict__ pred, const int* __restrict__ target,
                            float* __restrict__ L, u64* __restrict__ xp,
                            u64* __restrict__ acc64, u32* __restrict__ ticket) {
    int i = blockIdx.x * blockDim.x + threadIdx.x;
    if (i == 0) { acc64[0] = 0ULL; ticket[0] = 0u; }
    if (i >= NPIX) return;
    int b = i >> 18;
    int hw = i & (IMGPIX - 1);
    float p0 = pred[((size_t)(2 * b) << 18) + hw];
    float p1 = pred[((size_t)(2 * b + 1) << 18) + hw];
    // lse = max + log(1 + exp(-|p0-p1|)); fast HW transcendentals (threshold is 1.73 abs)
    float ad = fabsf(p0 - p1);
    float lse = fmaxf(p0, p1) + __logf(1.0f + __expf(-ad));
    int t = target[i];
    L[i] = lse - (t ? p1 : p0);            // -log_softmax[target]
    u64 word = __ballot(p1 > p0);          // 64 consecutive pixels per wave
    if ((threadIdx.x & 63) == 0) xp[i >> 6] = word;
}

// ---------------- bit-sliced helpers ----------------
#define FA(a,b,c,s,cy) { u64 _x = (a)^(b); (s) = _x^(c); (cy) = ((a)&(b)) | ((c)&_x); }
#define HA(a,b,s,cy)   { (s) = (a)^(b); (cy) = (a)&(b); }

// One ZS substep over a row of 8 words held in M[]; U/D are neighbor rows.
// Updates M in place; returns OR of deleted bits.
template<int FIRST>
__device__ __forceinline__ u64 zs_row(const u64* __restrict__ U, u64* __restrict__ M,
                                      const u64* __restrict__ D)
{
    u64 ch = 0;
    #pragma unroll
    for (int k = 0; k < WPR; ++k) {
        u64 Mc = M[k];
        if (Mc == 0ULL) continue;
        u64 Uc = U[k], Dc = D[k];
        u64 Up = k     ? U[k-1] : 0ULL;
        u64 Mp = k     ? M[k-1] : 0ULL;
        u64 Dp = k     ? D[k-1] : 0ULL;
        u64 Un = k < 7 ? U[k+1] : 0ULL;
        u64 Mn = k < 7 ? M[k+1] : 0ULL;
        u64 Dn = k < 7 ? D[k+1] : 0ULL;
        u64 P2 = Uc, P6 = Dc;
        u64 P3 = (Uc >> 1) | (Un << 63);
        u64 P4 = (Mc >> 1) | (Mn << 63);
        u64 P5 = (Dc >> 1) | (Dn << 63);
        u64 P9 = (Uc << 1) | (Up >> 63);
        u64 P8 = (Mc << 1) | (Mp >> 63);
        u64 P7 = (Dc << 1) | (Dp >> 63);

        u64 sa,ca, sb,cb, sc,cc, b0,cd, sd,ce, b1,cf, b2,b3;
        FA(P2,P3,P4, sa,ca);
        FA(P5,P6,P7, sb,cb);
        FA(P8,P9,sa, sc,cc);
        HA(sb,sc,    b0,cd);
        FA(ca,cb,cc, sd,ce);
        HA(sd,cd,    b1,cf);
        HA(ce,cf,    b2,b3);
        u64 ge2 = b1 | b2 | b3;
        u64 le6 = ~(b3 | (b0 & b1 & b2));

        u64 e, seen, two = 0;
        seen = (~P2) & P3;
        e = (~P3) & P4; two |= seen & e; seen |= e;
        e = (~P4) & P5; two |= seen & e; seen |= e;
        e = (~P5) & P6; two |= seen & e; seen |= e;
        e = (~P6) & P7; two |= seen & e; seen |= e;
        e = (~P7) & P8; two |= seen & e; seen |= e;
        e = (~P8) & P9; two |= seen & e; seen |= e;
        e = (~P9) & P2; two |= seen & e; seen |= e;
        u64 A1 = seen & ~two;

        u64 c34;
        if (FIRST) { u64 t = P4 & P6; c34 = t & (P2 | P8); }
        else       { u64 t = P2 & P8; c34 = t & (P4 | P6); }

        u64 del = Mc & ge2 & le6 & A1 & ~c34;
        M[k] = Mc ^ del;
        ch |= del;
    }
    return ch;
}

// swizzled word index into a [512][8] u64 buffer: XOR spreads row-start banks so the
// even word-stride (8) doesn't serialize (start banks cover all 16 pairs -> inherent-BW only)
__device__ __forceinline__ int sidx(int h, int k) {
    return (h << 3) + (k ^ ((h >> 1) & 7));
}

// ---------------- kernel 2: double-buffered single-block skeletonize + packed endpoints ----------------
// 8 blocks x 512 threads (thread = row). Own row in registers. TRUE double buffer:
// substep A reads buf0/writes buf1, ONE barrier, substep B reads buf1/writes buf0,
// one or-barrier -> 2 barriers per pair instead of 4 (the serial chain is the cost).
__global__ __launch_bounds__(512)
void skel_kernel(const u64* __restrict__ xp, u64* __restrict__ eg)
{
    __shared__ u64 buf[2][HH * WPR];       // 2 x 32 KB = 64 KB exactly, XOR-swizzled
    const int b = blockIdx.x;
    const int h = threadIdx.x;

    u64 M[WPR], U[WPR], D[WPR];
    const u64* src = xp + ((size_t)b << 12) + (size_t)h * WPR;
    #pragma unroll
    for (int k = 0; k < WPR; ++k) { M[k] = src[k]; buf[0][sidx(h, k)] = M[k]; }
    __syncthreads();

    const bool hasU = (h > 0), hasD = (h < HH - 1);

    for (int p = 0; p < MAXPAIR; ++p) {
        // ---- substep A: read buf0 neighbors, write own row to buf1
        #pragma unroll
        for (int k = 0; k < WPR; ++k) {
            U[k] = hasU ? buf[0][sidx(h - 1, k)] : 0ULL;
            D[k] = hasD ? buf[0][sidx(h + 1, k)] : 0ULL;
        }
        u64 chA = zs_row<1>(U, M, D);
        #pragma unroll
        for (int k = 0; k < WPR; ++k) buf[1][sidx(h, k)] = M[k];
        __syncthreads();

        // ---- substep B: read buf1 neighbors, write own row to buf0
        #pragma unroll
        for (int k = 0; k < WPR; ++k) {
            U[k] = hasU ? buf[1][sidx(h - 1, k)] : 0ULL;
            D[k] = hasD ? buf[1][sidx(h + 1, k)] : 0ULL;
        }
        u64 chB = zs_row<0>(U, M, D);
        #pragma unroll
        for (int k = 0; k < WPR; ++k) buf[0][sidx(h, k)] = M[k];
        if (!__syncthreads_or((chA | chB) != 0ULL)) break; // pair deleted nothing anywhere
    }

    // ---- endpoints E = skel & (exactly one 8-neighbor); state: buf0 + M regs (own row)
    #pragma unroll
    for (int k = 0; k < WPR; ++k) {
        U[k] = hasU ? buf[0][sidx(h - 1, k)] : 0ULL;
        D[k] = hasD ? buf[0][sidx(h + 1, k)] : 0ULL;
    }
    u64* egr = eg + ((size_t)b << 12) + (size_t)h * WPR;
    #pragma unroll
    for (int k = 0; k < WPR; ++k) {
        u64 Mc = M[k];
        u64 Uc = U[k], Dc = D[k];
        u64 Up = k     ? U[k-1] : 0ULL;
        u64 Mp = k     ? M[k-1] : 0ULL;
        u64 Dp = k     ? D[k-1] : 0ULL;
        u64 Un = k < 7 ? U[k+1] : 0ULL;
        u64 Mn = k < 7 ? M[k+1] : 0ULL;
        u64 Dn = k < 7 ? D[k+1] : 0ULL;
        u64 P2 = Uc, P6 = Dc;
        u64 P3 = (Uc >> 1) | (Un << 63);
        u64 P4 = (Mc >> 1) | (Mn << 63);
        u64 P5 = (Dc >> 1) | (Dn << 63);
        u64 P9 = (Uc << 1) | (Up >> 63);
        u64 P8 = (Mc << 1) | (Mp >> 63);
        u64 P7 = (Dc << 1) | (Dp >> 63);
        u64 e, seen, two = 0;
        seen = P2;
        e = P3; two |= seen & e; seen |= e;
        e = P4; two |= seen & e; seen |= e;
        e = P5; two |= seen & e; seen |= e;
        e = P6; two |= seen & e; seen |= e;
        e = P7; two |= seen & e; seen |= e;
        e = P8; two |= seen & e; seen |= e;
        e = P9; two |= seen & e; seen |= e;
        egr[k] = Mc & seen & ~two;             // exactly one neighbor
    }
}

// ---------------- packed 9x9 count helpers ----------------
struct Planes { u64 p0, p1, p2, p3; };

__device__ __forceinline__ Planes vcount9(const u64 r[9]) {
    u64 s0,c0, s1,c1, s2,c2, p0,t0, t1,t2, p1,t3, p2,p3;
    FA(r[0],r[1],r[2], s0,c0);
    FA(r[3],r[4],r[5], s1,c1);
    FA(r[6],r[7],r[8], s2,c2);
    FA(s0,s1,s2, p0,t0);
    FA(c0,c1,c2, t1,t2);
    HA(t0,t1,    p1,t3);
    HA(t2,t3,    p2,p3);
    Planes P; P.p0 = p0; P.p1 = p1; P.p2 = p2; P.p3 = p3; return P;
}

__device__ __forceinline__ u64 spread8(u64 bb) {
    u64 s = (bb * 0x0101010101010101ULL) & 0x8040201008040201ULL;
    return ((s + 0x7f7f7f7f7f7f7f7fULL) >> 7) & 0x0101010101010101ULL;
}

__device__ __forceinline__ u64 vbytes(const Planes& P, int g) {
    int s = 8 * g;
    return  spread8((P.p0 >> s) & 0xFFULL)
         + (spread8((P.p1 >> s) & 0xFFULL) << 1)
         + (spread8((P.p2 >> s) & 0xFFULL) << 2)
         + (spread8((P.p3 >> s) & 0xFFULL) << 3);
}

// ---------------- kernel 3: dense weighted sum ----------------
// w_i = 60*n_i + [n_i==0], n_i = 9x9 box count of E;  out = mean(w*L)
__global__ __launch_bounds__(256)
void final_kernel(const float* __restrict__ L, const u64* __restrict__ eg,
                  u64* __restrict__ acc64, u32* __restrict__ ticket,
                  float* __restrict__ out) {
    __shared__ float sm[256];
    int wi = blockIdx.x * blockDim.x + threadIdx.x;   // word index, 32768 total
    int b  = wi >> 12;                                // 4096 words / image
    int h  = (wi >> 3) & (HH - 1);
    int wc = wi & 7;
    const u64* img = eg + ((size_t)b << 12);

    u64 rows[3][9];
    #pragma unroll
    for (int dh = -4; dh <= 4; ++dh) {
        int hh = h + dh;
        bool okh = (unsigned)hh < (unsigned)HH;
        const u64* rp = img + hh * WPR;
        rows[0][dh + 4] = (okh && wc > 0) ? rp[wc - 1] : 0ULL;
        rows[1][dh + 4] = okh             ? rp[wc]     : 0ULL;
        rows[2][dh + 4] = (okh && wc < 7) ? rp[wc + 1] : 0ULL;
    }
    Planes Pm = vcount9(rows[0]);
    Planes Pc = vcount9(rows[1]);
    Planes Pp = vcount9(rows[2]);

    u64 v[10];
    v[0] = vbytes(Pm, 7);
    #pragma unroll
    for (int g = 0; g < 8; ++g) v[g + 1] = vbytes(Pc, g);
    v[9] = vbytes(Pp, 0);

    const float4* Lr = (const float4*)(L + ((size_t)wi << 6));
    float acc = 0.0f;
    #pragma unroll
    for (int g = 0; g < 8; ++g) {
        u64 a = v[g + 1], lo = v[g], hi = v[g + 2];
        u64 n = a;
        #pragma unroll
        for (int d = 1; d <= 4; ++d) {
            n += (a >> (8 * d)) | (hi << (64 - 8 * d));
            n += (a << (8 * d)) | (lo >> (64 - 8 * d));
        }
        float4 f0 = Lr[2 * g], f1 = Lr[2 * g + 1];
        #pragma unroll
        for (int j = 0; j < 8; ++j) {
            int cnt = (int)((n >> (8 * j)) & 0xFFULL);
            float wgt = cnt ? (float)(60 * cnt) : 1.0f;
            float lv = (j < 4) ? ((j == 0) ? f0.x : (j == 1) ? f0.y : (j == 2) ? f0.z : f0.w)
                               : ((j == 4) ? f1.x : (j == 5) ? f1.y : (j == 6) ? f1.z : f1.w);
            acc += wgt * lv;
        }
    }

    sm[threadIdx.x] = acc;
    __syncthreads();
    for (int s = 128; s > 0; s >>= 1) {
        if (threadIdx.x < s) sm[threadIdx.x] += sm[threadIdx.x + s];
        __syncthreads();
    }
    if (threadIdx.x == 0) {
        u64 vfx = (u64)(long long)llrintf(sm[0] * (float)FPSCALE);
        atomicAdd(acc64, vfx);
        __threadfence();
        u32 t = atomicAdd(ticket, 1u);
        if (t == (u32)(gridDim.x - 1)) {           // last block finishes
            __threadfence();
            u64 total = __hip_atomic_load(acc64, __ATOMIC_RELAXED, __HIP_MEMORY_SCOPE_AGENT);
            out[0] = (float)((double)(long long)total / (FPSCALE * (double)NPIX));
        }
    }
}

extern "C" void kernel_launch(void* const* d_in, const int* in_sizes, int n_in,
                              void* d_out, int out_size, void* d_ws, size_t ws_size,
                              hipStream_t stream) {
    const float* pred = (const float*)d_in[0];
    const int* target = (const int*)d_in[1];
    float* out = (float*)d_out;
    char* ws = (char*)d_ws;

    // ws layout (bytes):
    //   [0,        8388608)  L       float[NPIX]
    //   [8388608,  8650752)  xp      u64[NWORDS]  packed mask
    //   [8650752,  8912896)  eg      u64[NWORDS]  packed endpoints
    //   [8912896,  8912904)  acc64   u64
    //   [8912904,  8912908)  ticket  u32
    float* L    = (float*)(ws);
    u64* xp     = (u64*)(ws + 8388608);
    u64* eg     = (u64*)(ws + 8650752);
    u64* acc64  = (u64*)(ws + 8912896);
    u32* ticket = (u32*)(ws + 8912904);

    prep_kernel<<<dim3(NPIX / 256), dim3(256), 0, stream>>>(pred, target, L, xp, acc64, ticket);
    skel_kernel<<<dim3(BATCH), dim3(512), 0, stream>>>(xp, eg);
    final_kernel<<<dim3(NWORDS / 256), dim3(256), 0, stream>>>(L, eg, acc64, ticket, out);
}